// Round 6
// baseline (174.911 us; speedup 1.0000x reference)
//
#include <hip/hip_runtime.h>
#include <hip/hip_bf16.h>

#define B_  2
#define S_  2048
#define D_  1024
#define H_  16
#define DK_ 64
#define M_  (B_ * S_)   // 4096

typedef short short8 __attribute__((ext_vector_type(8)));
typedef float float4v __attribute__((ext_vector_type(4)));

// log2(e)/8 : folded into Q at projection so attention exp is a bare v_exp_f32
#define QSCALE 0.18033688011112042f

static __device__ __forceinline__ ushort f32_to_bf16bits(float f) {
    union { __hip_bfloat16 h; ushort u; } cv;
    cv.h = __float2bfloat16(f);
    return cv.u;
}
static __device__ __forceinline__ unsigned pk2(float a, float b) {
    return (unsigned)f32_to_bf16bits(a) | ((unsigned)f32_to_bf16bits(b) << 16);
}

// async global->LDS, 16B per lane (lands at wave-uniform base + lane*16)
static __device__ __forceinline__ void glds16(const ushort* g, ushort* l) {
    __builtin_amdgcn_global_load_lds(
        (const __attribute__((address_space(1))) unsigned int*)g,
        (__attribute__((address_space(3))) unsigned int*)l, 16, 0, 0);
}

// ---------------------------------------------------------------------------
// prep: z in [0,3) -> transpose+convert W_z[k][n] fp32 -> Wt[n][k] bf16
//       z in [3,11) -> convert X fp32 -> bf16
// ---------------------------------------------------------------------------
__global__ __launch_bounds__(256) void prep(
    const float* __restrict__ X, const float* __restrict__ W0,
    const float* __restrict__ W1, const float* __restrict__ W2,
    ushort* __restrict__ Xb, ushort* __restrict__ Wt)
{
    const int z = blockIdx.z;
    const int t = threadIdx.x;

    if (z >= 3) {   // convert X
        const int blk = (z - 3) * 256 + blockIdx.y * 16 + blockIdx.x;
        const int i = blk * 2048 + t * 8;
        float4v a = *(const float4v*)(X + i);
        float4v b = *(const float4v*)(X + i + 4);
        short8 o;
        o[0] = (short)f32_to_bf16bits(a[0]); o[1] = (short)f32_to_bf16bits(a[1]);
        o[2] = (short)f32_to_bf16bits(a[2]); o[3] = (short)f32_to_bf16bits(a[3]);
        o[4] = (short)f32_to_bf16bits(b[0]); o[5] = (short)f32_to_bf16bits(b[1]);
        o[6] = (short)f32_to_bf16bits(b[2]); o[7] = (short)f32_to_bf16bits(b[3]);
        *(short8*)(Xb + i) = o;
        return;
    }

    const float* W = (z == 0) ? W0 : ((z == 1) ? W1 : W2);
    ushort* out = Wt + (size_t)z * D_ * D_;

    __shared__ ushort tile[64 * 72];
    int n0 = blockIdx.x * 64, k0 = blockIdx.y * 64;
    int r = t >> 3, g = t & 7;

    #pragma unroll
    for (int p = 0; p < 2; ++p) {
        int rr = r + p * 32;
        const float* src = W + (size_t)(k0 + rr) * D_ + n0 + g * 8;
        float4v a = *(const float4v*)src;
        float4v b = *(const float4v*)(src + 4);
        short8 o;
        o[0] = (short)f32_to_bf16bits(a[0]); o[1] = (short)f32_to_bf16bits(a[1]);
        o[2] = (short)f32_to_bf16bits(a[2]); o[3] = (short)f32_to_bf16bits(a[3]);
        o[4] = (short)f32_to_bf16bits(b[0]); o[5] = (short)f32_to_bf16bits(b[1]);
        o[6] = (short)f32_to_bf16bits(b[2]); o[7] = (short)f32_to_bf16bits(b[3]);
        *(short8*)&tile[rr * 72 + g * 8] = o;
    }
    __syncthreads();
    #pragma unroll
    for (int p = 0; p < 2; ++p) {
        int rr = r + p * 32;
        short8 v;
        #pragma unroll
        for (int i = 0; i < 8; ++i)
            v[i] = (short)tile[(g * 8 + i) * 72 + rr];
        *(short8*)(out + (size_t)(n0 + rr) * D_ + k0 + g * 8) = v;
    }
}

// ---------------------------------------------------------------------------
// fused QKV projection: 128x128 tile, BK=64, glds16 + XOR swizzle, double-
// buffered.  Grid is FLAT with z fastest (z = bx%3) so q/k/v blocks are
// co-resident on every CU (the z-major grid phase-separated them and the
// k/v skip holes starved occupancy).  k/v m-tiles beyond length[b] skipped.
// z==0 (Q) epilogue folds score-scale*log2(e) into the values.
// ---------------------------------------------------------------------------
__global__ __launch_bounds__(256, 2) void proj_gemm(
    const ushort* __restrict__ X,    // [4096][1024] bf16
    const ushort* __restrict__ Wt,   // [3][1024][1024] bf16, n-major
    const float* __restrict__ b0, const float* __restrict__ b1,
    const float* __restrict__ b2,
    const int* __restrict__ length,
    ushort* __restrict__ qkv)        // [3][4M] bf16
{
    const int bx = blockIdx.x;
    const int z  = bx % 3;
    const int rem = bx / 3;
    const int m0 = (rem & 31) * 128;       // m fastest after z
    const int n0 = (rem >> 5) * 128;

    if (z >= 1) {   // k/v: skip tiles fully beyond this batch's length
        const int bidx = m0 >> 11;
        const int s0 = m0 & (S_ - 1);
        if (s0 >= length[bidx]) return;
    }

    const ushort* Wtz  = Wt + (size_t)z * D_ * D_;
    const float* bias = (z == 0) ? b0 : ((z == 1) ? b1 : b2);
    ushort* out = qkv + (size_t)z * M_ * D_;

    __shared__ __align__(16) ushort As[2][128 * 64];   // 2 x 16 KB
    __shared__ __align__(16) ushort Bs[2][128 * 64];   // 2 x 16 KB

    const int t = threadIdx.x;
    const int lane = t & 63, wid = t >> 6;
    const int quad = lane >> 4, l16 = lane & 15;
    const int wr = wid >> 1, wc = wid & 1;

    float4v acc[4][4] = {};

    // stage k-tile 0 into buffer 0: 1024 chunks each of A,B; 4 glds/wave each
    #pragma unroll
    for (int j = 0; j < 4; ++j) {
        const int cid = wid * 256 + j * 64 + lane;
        const int row = cid >> 3;
        const int cl  = (cid & 7) ^ (row & 7);
        glds16(X   + (size_t)(m0 + row) * D_ + cl * 8, &As[0][cid * 8]);
        glds16(Wtz + (size_t)(n0 + row) * D_ + cl * 8, &Bs[0][cid * 8]);
    }
    __syncthreads();

    for (int kt = 0; kt < 16; ++kt) {
        const int cur = kt & 1, nxt = cur ^ 1;
        if (kt + 1 < 16) {
            const int k0 = (kt + 1) * 64;
            #pragma unroll
            for (int j = 0; j < 4; ++j) {
                const int cid = wid * 256 + j * 64 + lane;
                const int row = cid >> 3;
                const int cl  = (cid & 7) ^ (row & 7);
                glds16(X   + (size_t)(m0 + row) * D_ + k0 + cl * 8, &As[nxt][cid * 8]);
                glds16(Wtz + (size_t)(n0 + row) * D_ + k0 + cl * 8, &Bs[nxt][cid * 8]);
            }
        }

        #pragma unroll
        for (int ks = 0; ks < 2; ++ks) {
            short8 a[4], bb[4];
            #pragma unroll
            for (int i = 0; i < 4; ++i) {
                const int r = wr * 64 + i * 16 + l16;
                const int ph = (ks * 4 + quad) ^ (r & 7);
                a[i] = *(short8*)&As[cur][r * 64 + ph * 8];
            }
            #pragma unroll
            for (int j = 0; j < 4; ++j) {
                const int r = wc * 64 + j * 16 + l16;
                const int ph = (ks * 4 + quad) ^ (r & 7);
                bb[j] = *(short8*)&Bs[cur][r * 64 + ph * 8];
            }
            #pragma unroll
            for (int i = 0; i < 4; ++i)
                #pragma unroll
                for (int j = 0; j < 4; ++j)
                    acc[i][j] = __builtin_amdgcn_mfma_f32_16x16x32_bf16(
                        a[i], bb[j], acc[i][j], 0, 0, 0);
        }
        __syncthreads();   // drains next-stage glds (in flight during compute)
    }

    // epilogue: +bias; z==0 pre-scales by log2(e)/8; scatter into head layout
    const float sc = (z == 0) ? QSCALE : 1.0f;
    #pragma unroll
    for (int j = 0; j < 4; ++j) {
        const int col = n0 + wc * 64 + j * 16 + l16;
        const float bv = bias[col];
        const int h = col >> 6, dk = col & (DK_ - 1);
        #pragma unroll
        for (int i = 0; i < 4; ++i) {
            #pragma unroll
            for (int rr = 0; rr < 4; ++rr) {
                const int row = m0 + wr * 64 + i * 16 + quad * 4 + rr;
                const int bidx = row >> 11;
                const int s = row & (S_ - 1);
                const float v = (acc[i][j][rr] + bv) * sc;
                size_t addr;
                if (z == 2)
                    addr = ((size_t)(bidx * H_ + h) * DK_ + dk) * S_ + s;
                else
                    addr = ((size_t)(bidx * H_ + h) * S_ + s) * DK_ + dk;
                out[addr] = f32_to_bf16bits(v);
            }
        }
    }
}

// ---------------------------------------------------------------------------
// attention: block = (b, h, 64 q-rows), 4 waves x 16-q strips.
// S^T trick: compute S^T = K*Q^T so the MFMA C-layout hands each lane 4
// CONSECUTIVE keys per q -> P strip written as 4 packed ds_write_b64.
// Even-XOR 8B-chunk swizzle on Ps keeps PV's ds_read_b128 legal and ~free.
// Q pre-scaled at projection: score exp = bare v_exp_f32.
// K/V staging double-buffered; interior tiles skip mask cmps.
// ---------------------------------------------------------------------------
__global__ __launch_bounds__(256, 3) void attention(
    const ushort* __restrict__ qkv, const int* __restrict__ length,
    float* __restrict__ out)
{
    const int b = blockIdx.z, h = blockIdx.y, q0 = blockIdx.x * 64;
    int len = length[b];
    if (len > S_) len = S_;
    if (len < 1) len = 1;
    const int nkt = (len + 63) >> 6;

    const ushort* qb = qkv + ((size_t)(b * H_ + h) * S_ + q0) * DK_;
    const ushort* kb = qkv + (size_t)M_ * D_ + (size_t)(b * H_ + h) * S_ * DK_;
    const ushort* vb = qkv + (size_t)2 * M_ * D_ + (size_t)(b * H_ + h) * DK_ * S_;

    __shared__ __align__(16) ushort Qs[64 * 64];       //  8 KB [q][dk]
    __shared__ __align__(16) ushort Ks[2][64 * 64];    // 16 KB [key][dk]
    __shared__ __align__(16) ushort Vs[2][64 * 64];    // 16 KB [dk][key]
    __shared__ __align__(16) ushort Ps[64 * 64];       //  8 KB [q][key], 8B-swizzle

    const int t = threadIdx.x, lane = t & 63, wid = t >> 6;
    const int quad = lane >> 4, l16 = lane & 15;
    const int qrow = wid * 16 + l16;
    const int e8 = (l16 & 7) << 1;   // even XOR phase for Ps (row&7 == l16&7)

    // stage Q (once) + K/V tile 0
    #pragma unroll
    for (int j = 0; j < 2; ++j) {
        const int cid = wid * 128 + j * 64 + lane;
        const int row = cid >> 3;
        const int cl  = (cid & 7) ^ (row & 7);
        glds16(qb + (size_t)row * DK_ + cl * 8, &Qs[cid * 8]);
        glds16(kb + (size_t)row * DK_ + cl * 8, &Ks[0][cid * 8]);
        glds16(vb + (size_t)row * S_ + cl * 8,  &Vs[0][cid * 8]);
    }
    __syncthreads();

    float4v cacc[4] = {};
    float rs = 0.f;

    for (int kt = 0; kt < nkt; ++kt) {
        const int cur = kt & 1, nxt = cur ^ 1;
        if (kt + 1 < nkt) {
            #pragma unroll
            for (int j = 0; j < 2; ++j) {
                const int cid = wid * 128 + j * 64 + lane;
                const int row = cid >> 3;
                const int cl  = (cid & 7) ^ (row & 7);
                glds16(kb + (size_t)((kt + 1) * 64 + row) * DK_ + cl * 8,
                       &Ks[nxt][cid * 8]);
                glds16(vb + (size_t)row * S_ + (kt + 1) * 64 + cl * 8,
                       &Vs[nxt][cid * 8]);
            }
        }

        // S^T tile: A = K-frag (m=key), B = Q-frag (n=q).  D[key][q]:
        // lane holds q = l16 (col), keys = ct*16 + quad*4 + rr (rows).
        float4v sacc[4] = {};
        #pragma unroll
        for (int ks = 0; ks < 2; ++ks) {
            const int phb = (ks * 4 + quad) ^ (l16 & 7);
            short8 bq8 = *(short8*)&Qs[qrow * 64 + phb * 8];
            #pragma unroll
            for (int ct = 0; ct < 4; ++ct) {
                const int krow = ct * 16 + l16;
                const int pha = (ks * 4 + quad) ^ (krow & 7);
                short8 ak = *(short8*)&Ks[cur][krow * 64 + pha * 8];
                sacc[ct] = __builtin_amdgcn_mfma_f32_16x16x32_bf16(
                    ak, bq8, sacc[ct], 0, 0, 0);
            }
        }

        // exp2 + (boundary-only) mask + rowsum + packed P write
        const bool full = ((kt + 1) * 64 <= len);
        #pragma unroll
        for (int ct = 0; ct < 4; ++ct) {
            float v0 = __builtin_amdgcn_exp2f(sacc[ct][0]);
            float v1 = __builtin_amdgcn_exp2f(sacc[ct][1]);
            float v2 = __builtin_amdgcn_exp2f(sacc[ct][2]);
            float v3 = __builtin_amdgcn_exp2f(sacc[ct][3]);
            if (!full) {
                const int kb0 = kt * 64 + ct * 16 + quad * 4;
                v0 = (kb0 + 0 < len) ? v0 : 0.f;
                v1 = (kb0 + 1 < len) ? v1 : 0.f;
                v2 = (kb0 + 2 < len) ? v2 : 0.f;
                v3 = (kb0 + 3 < len) ? v3 : 0.f;
            }
            rs += (v0 + v1) + (v2 + v3);
            uint2 w;
            w.x = pk2(v0, v1);
            w.y = pk2(v2, v3);
            const int c8 = (ct * 4 + quad) ^ e8;        // 8B-chunk swizzle
            *(uint2*)&Ps[qrow * 64 + c8 * 4] = w;
        }

        // P @ V: A = P-frag (m=q, k=key), B = V-frag from Vs (n=d).
        // Strip is wave-private: same-wave LDS RAW, no barrier needed.
        #pragma unroll
        for (int ks = 0; ks < 2; ++ks) {
            const int pp = ((ks * 4 + quad) * 2) ^ e8;   // first 8B chunk (even)
            short8 ap = *(short8*)&Ps[qrow * 64 + pp * 4];
            #pragma unroll
            for (int ct = 0; ct < 4; ++ct) {
                const int vrow = ct * 16 + l16;
                const int phv = (ks * 4 + quad) ^ (vrow & 7);
                short8 vv = *(short8*)&Vs[cur][vrow * 64 + phv * 8];
                cacc[ct] = __builtin_amdgcn_mfma_f32_16x16x32_bf16(
                    ap, vv, cacc[ct], 0, 0, 0);
            }
        }
        __syncthreads();   // next-stage glds drained; buf[cur] free for kt+2
    }

    // row-sum: lane holds partial for q = l16-group; reduce across quads
    rs += __shfl_xor(rs, 16);
    rs += __shfl_xor(rs, 32);

    // normalize + store fp32.  C-layout: col = d-offset = l16, row = q-offset
    // = quad*4+rr; fetch rs(q=quad*4+rr) from lane group via width-16 shuffle.
    #pragma unroll
    for (int rr = 0; rr < 4; ++rr) {
        const float rsq = __shfl(rs, quad * 4 + rr, 16);
        const float inv = 1.0f / (rsq + 1e-8f);
        const int q = q0 + wid * 16 + quad * 4 + rr;
        #pragma unroll
        for (int ct = 0; ct < 4; ++ct) {
            const int d = h * 64 + ct * 16 + l16;
            out[((size_t)b * S_ + q) * D_ + d] = cacc[ct][rr] * inv;
        }
    }
}

// ---------------------------------------------------------------------------
extern "C" void kernel_launch(void* const* d_in, const int* in_sizes, int n_in,
                              void* d_out, int out_size, void* d_ws, size_t ws_size,
                              hipStream_t stream)
{
    const float* Q   = (const float*)d_in[0];
    const int*   len = (const int*)d_in[1];
    const float* Wq  = (const float*)d_in[2];
    const float* bq  = (const float*)d_in[3];
    const float* Wk  = (const float*)d_in[4];
    const float* bk  = (const float*)d_in[5];
    const float* Wv  = (const float*)d_in[6];
    const float* bv  = (const float*)d_in[7];
    float* out = (float*)d_out;

    ushort* ws  = (ushort*)d_ws;
    ushort* Xb  = ws;                                   // 4M bf16 = 8 MB
    ushort* Wt  = ws + (size_t)M_ * D_;                 // 3M bf16 = 6 MB
    ushort* qkv = Wt + (size_t)3 * D_ * D_;             // 12M bf16 = 24 MB

    dim3 gPr(16, 16, 11);
    prep<<<gPr, 256, 0, stream>>>(Q, Wq, Wk, Wv, Xb, Wt);

    // flat grid, z fastest: 32 m-tiles x 8 n-tiles x 3 mats
    proj_gemm<<<dim3(32 * 8 * 3), 256, 0, stream>>>(Xb, Wt, bq, bk, bv, len, qkv);

    dim3 gA(S_ / 64, H_, B_);
    attention<<<gA, 256, 0, stream>>>(qkv, len, out);
}

// Round 7
// 157.209 us; speedup vs baseline: 1.1126x; 1.1126x over previous
//
#include <hip/hip_runtime.h>
#include <hip/hip_bf16.h>

#define B_  2
#define S_  2048
#define D_  1024
#define H_  16
#define DK_ 64
#define M_  (B_ * S_)   // 4096

typedef short short8 __attribute__((ext_vector_type(8)));
typedef float float4v __attribute__((ext_vector_type(4)));

// log2(e)/8 : folded into Q at projection so attention exp is a bare v_exp_f32
#define QSCALE 0.18033688011112042f

static __device__ __forceinline__ ushort f32_to_bf16bits(float f) {
    union { __hip_bfloat16 h; ushort u; } cv;
    cv.h = __float2bfloat16(f);
    return cv.u;
}
static __device__ __forceinline__ unsigned pk2(float a, float b) {
    return (unsigned)f32_to_bf16bits(a) | ((unsigned)f32_to_bf16bits(b) << 16);
}

// async global->LDS, 16B per lane (lands at wave-uniform base + lane*16)
static __device__ __forceinline__ void glds16(const ushort* g, ushort* l) {
    __builtin_amdgcn_global_load_lds(
        (const __attribute__((address_space(1))) unsigned int*)g,
        (__attribute__((address_space(3))) unsigned int*)l, 16, 0, 0);
}

// ---------------------------------------------------------------------------
// prep: z in [0,3) -> transpose+convert W_z[k][n] fp32 -> Wt[n][k] bf16
//       z in [3,11) -> convert X fp32 -> bf16
// ---------------------------------------------------------------------------
__global__ __launch_bounds__(256) void prep(
    const float* __restrict__ X, const float* __restrict__ W0,
    const float* __restrict__ W1, const float* __restrict__ W2,
    ushort* __restrict__ Xb, ushort* __restrict__ Wt)
{
    const int z = blockIdx.z;
    const int t = threadIdx.x;

    if (z >= 3) {   // convert X
        const int blk = (z - 3) * 256 + blockIdx.y * 16 + blockIdx.x;
        const int i = blk * 2048 + t * 8;
        float4v a = *(const float4v*)(X + i);
        float4v b = *(const float4v*)(X + i + 4);
        short8 o;
        o[0] = (short)f32_to_bf16bits(a[0]); o[1] = (short)f32_to_bf16bits(a[1]);
        o[2] = (short)f32_to_bf16bits(a[2]); o[3] = (short)f32_to_bf16bits(a[3]);
        o[4] = (short)f32_to_bf16bits(b[0]); o[5] = (short)f32_to_bf16bits(b[1]);
        o[6] = (short)f32_to_bf16bits(b[2]); o[7] = (short)f32_to_bf16bits(b[3]);
        *(short8*)(Xb + i) = o;
        return;
    }

    const float* W = (z == 0) ? W0 : ((z == 1) ? W1 : W2);
    ushort* out = Wt + (size_t)z * D_ * D_;

    __shared__ ushort tile[64 * 72];
    int n0 = blockIdx.x * 64, k0 = blockIdx.y * 64;
    int r = t >> 3, g = t & 7;

    #pragma unroll
    for (int p = 0; p < 2; ++p) {
        int rr = r + p * 32;
        const float* src = W + (size_t)(k0 + rr) * D_ + n0 + g * 8;
        float4v a = *(const float4v*)src;
        float4v b = *(const float4v*)(src + 4);
        short8 o;
        o[0] = (short)f32_to_bf16bits(a[0]); o[1] = (short)f32_to_bf16bits(a[1]);
        o[2] = (short)f32_to_bf16bits(a[2]); o[3] = (short)f32_to_bf16bits(a[3]);
        o[4] = (short)f32_to_bf16bits(b[0]); o[5] = (short)f32_to_bf16bits(b[1]);
        o[6] = (short)f32_to_bf16bits(b[2]); o[7] = (short)f32_to_bf16bits(b[3]);
        *(short8*)&tile[rr * 72 + g * 8] = o;
    }
    __syncthreads();
    #pragma unroll
    for (int p = 0; p < 2; ++p) {
        int rr = r + p * 32;
        short8 v;
        #pragma unroll
        for (int i = 0; i < 8; ++i)
            v[i] = (short)tile[(g * 8 + i) * 72 + rr];
        *(short8*)(out + (size_t)(n0 + rr) * D_ + k0 + g * 8) = v;
    }
}

// ---------------------------------------------------------------------------
// FUSED-z QKV projection: one block = (m-tile 64, n-tile 128) computing q, k
// AND v.  A (X panel) is staged ONCE and reused for all three B panels ->
// 48 MFMA per barrier (vs 16) against the same per-iteration drain; A-LDS
// traffic / glds count drop ~2.3x.  56 KB LDS single-buffered = 2 blocks/CU.
// k/v work skipped (block-uniform) when this m-tile is beyond length[b].
// z==0 (Q) epilogue folds score-scale*log2(e) into the values.
// ---------------------------------------------------------------------------
__global__ __launch_bounds__(256, 2) void proj_gemm(
    const ushort* __restrict__ X,    // [4096][1024] bf16
    const ushort* __restrict__ Wt,   // [3][1024][1024] bf16, n-major
    const float* __restrict__ b0, const float* __restrict__ b1,
    const float* __restrict__ b2,
    const int* __restrict__ length,
    ushort* __restrict__ qkv)        // [3][4M] bf16
{
    const int m0 = blockIdx.x * 64, n0 = blockIdx.y * 128;
    const int bidx = m0 >> 11;
    const int s0 = m0 & (S_ - 1);
    const bool kv = (s0 < length[bidx]);   // block-uniform

    __shared__ __align__(16) ushort As[64 * 64];        //  8 KB
    __shared__ __align__(16) ushort Bs[3][128 * 64];    // 48 KB

    const int t = threadIdx.x;
    const int lane = t & 63, wid = t >> 6;
    const int quad = lane >> 4, l16 = lane & 15;
    const int wr = wid >> 1, wc = wid & 1;

    float4v accq[2][4] = {}, acck[2][4] = {}, accv[2][4] = {};

    for (int kt = 0; kt < 16; ++kt) {
        const int k0 = kt * 64;
        __syncthreads();
        #pragma unroll
        for (int j = 0; j < 2; ++j) {          // A: 512 chunks, 128/wave
            const int cid = wid * 128 + j * 64 + lane;
            const int row = cid >> 3;
            const int cl  = (cid & 7) ^ (row & 7);
            glds16(X + (size_t)(m0 + row) * D_ + k0 + cl * 8, &As[cid * 8]);
        }
        #pragma unroll
        for (int j = 0; j < 4; ++j) {          // B panels: 1024 chunks each
            const int cid = wid * 256 + j * 64 + lane;
            const int row = cid >> 3;
            const int cl  = (cid & 7) ^ (row & 7);
            const size_t off = (size_t)(n0 + row) * D_ + k0 + cl * 8;
            glds16(Wt + off, &Bs[0][cid * 8]);
            if (kv) {
                glds16(Wt + (size_t)D_ * D_ + off,     &Bs[1][cid * 8]);
                glds16(Wt + (size_t)2 * D_ * D_ + off, &Bs[2][cid * 8]);
            }
        }
        __syncthreads();

        #pragma unroll
        for (int ks = 0; ks < 2; ++ks) {
            short8 a[2];
            #pragma unroll
            for (int i = 0; i < 2; ++i) {
                const int r = wr * 32 + i * 16 + l16;
                const int ph = (ks * 4 + quad) ^ (r & 7);
                a[i] = *(short8*)&As[r * 64 + ph * 8];
            }
            short8 bq[4];
            #pragma unroll
            for (int j = 0; j < 4; ++j) {
                const int r = wc * 64 + j * 16 + l16;
                const int ph = (ks * 4 + quad) ^ (r & 7);
                bq[j] = *(short8*)&Bs[0][r * 64 + ph * 8];
            }
            #pragma unroll
            for (int i = 0; i < 2; ++i)
                #pragma unroll
                for (int j = 0; j < 4; ++j)
                    accq[i][j] = __builtin_amdgcn_mfma_f32_16x16x32_bf16(
                        a[i], bq[j], accq[i][j], 0, 0, 0);
            if (kv) {
                short8 bk[4], bv[4];
                #pragma unroll
                for (int j = 0; j < 4; ++j) {
                    const int r = wc * 64 + j * 16 + l16;
                    const int ph = (ks * 4 + quad) ^ (r & 7);
                    bk[j] = *(short8*)&Bs[1][r * 64 + ph * 8];
                    bv[j] = *(short8*)&Bs[2][r * 64 + ph * 8];
                }
                #pragma unroll
                for (int i = 0; i < 2; ++i)
                    #pragma unroll
                    for (int j = 0; j < 4; ++j) {
                        acck[i][j] = __builtin_amdgcn_mfma_f32_16x16x32_bf16(
                            a[i], bk[j], acck[i][j], 0, 0, 0);
                        accv[i][j] = __builtin_amdgcn_mfma_f32_16x16x32_bf16(
                            a[i], bv[j], accv[i][j], 0, 0, 0);
                    }
            }
        }
    }

    // epilogue: +bias, scatter into head layouts.
    #pragma unroll
    for (int j = 0; j < 4; ++j) {
        const int col = n0 + wc * 64 + j * 16 + l16;
        const int h = col >> 6, dk = col & (DK_ - 1);
        const float bvq = b0[col], bvk = b1[col], bvv = b2[col];
        #pragma unroll
        for (int i = 0; i < 2; ++i) {
            #pragma unroll
            for (int rr = 0; rr < 4; ++rr) {
                const int row = m0 + wr * 32 + i * 16 + quad * 4 + rr;
                const int s = row & (S_ - 1);
                const size_t hdr = ((size_t)(bidx * H_ + h) * S_ + s) * DK_ + dk;
                qkv[hdr] = f32_to_bf16bits((accq[i][j][rr] + bvq) * QSCALE);
                if (kv) {
                    qkv[(size_t)M_ * D_ + hdr] =
                        f32_to_bf16bits(acck[i][j][rr] + bvk);
                    qkv[(size_t)2 * M_ * D_ +
                        ((size_t)(bidx * H_ + h) * DK_ + dk) * S_ + s] =
                        f32_to_bf16bits(accv[i][j][rr] + bvv);
                }
            }
        }
    }
}

// ---------------------------------------------------------------------------
// attention: block = (b, h, 64 q-rows), 4 waves x 16-q strips.
// S^T trick: compute S^T = K*Q^T so the MFMA C-layout hands each lane 4
// CONSECUTIVE keys per q -> P strip written as 4 packed ds_write_b64.
// Even-XOR 8B-chunk swizzle on Ps keeps PV's ds_read_b128 legal and ~free.
// Q pre-scaled at projection: score exp = bare v_exp_f32.
// K/V staging double-buffered; interior tiles skip mask cmps.
// ---------------------------------------------------------------------------
__global__ __launch_bounds__(256, 3) void attention(
    const ushort* __restrict__ qkv, const int* __restrict__ length,
    float* __restrict__ out)
{
    const int b = blockIdx.z, h = blockIdx.y, q0 = blockIdx.x * 64;
    int len = length[b];
    if (len > S_) len = S_;
    if (len < 1) len = 1;
    const int nkt = (len + 63) >> 6;

    const ushort* qb = qkv + ((size_t)(b * H_ + h) * S_ + q0) * DK_;
    const ushort* kb = qkv + (size_t)M_ * D_ + (size_t)(b * H_ + h) * S_ * DK_;
    const ushort* vb = qkv + (size_t)2 * M_ * D_ + (size_t)(b * H_ + h) * DK_ * S_;

    __shared__ __align__(16) ushort Qs[64 * 64];       //  8 KB [q][dk]
    __shared__ __align__(16) ushort Ks[2][64 * 64];    // 16 KB [key][dk]
    __shared__ __align__(16) ushort Vs[2][64 * 64];    // 16 KB [dk][key]
    __shared__ __align__(16) ushort Ps[64 * 64];       //  8 KB [q][key], 8B-swizzle

    const int t = threadIdx.x, lane = t & 63, wid = t >> 6;
    const int quad = lane >> 4, l16 = lane & 15;
    const int qrow = wid * 16 + l16;
    const int e8 = (l16 & 7) << 1;   // even XOR phase for Ps (row&7 == l16&7)

    // stage Q (once) + K/V tile 0
    #pragma unroll
    for (int j = 0; j < 2; ++j) {
        const int cid = wid * 128 + j * 64 + lane;
        const int row = cid >> 3;
        const int cl  = (cid & 7) ^ (row & 7);
        glds16(qb + (size_t)row * DK_ + cl * 8, &Qs[cid * 8]);
        glds16(kb + (size_t)row * DK_ + cl * 8, &Ks[0][cid * 8]);
        glds16(vb + (size_t)row * S_ + cl * 8,  &Vs[0][cid * 8]);
    }
    __syncthreads();

    float4v cacc[4] = {};
    float rs = 0.f;

    for (int kt = 0; kt < nkt; ++kt) {
        const int cur = kt & 1, nxt = cur ^ 1;
        if (kt + 1 < nkt) {
            #pragma unroll
            for (int j = 0; j < 2; ++j) {
                const int cid = wid * 128 + j * 64 + lane;
                const int row = cid >> 3;
                const int cl  = (cid & 7) ^ (row & 7);
                glds16(kb + (size_t)((kt + 1) * 64 + row) * DK_ + cl * 8,
                       &Ks[nxt][cid * 8]);
                glds16(vb + (size_t)row * S_ + (kt + 1) * 64 + cl * 8,
                       &Vs[nxt][cid * 8]);
            }
        }

        // S^T tile: A = K-frag (m=key), B = Q-frag (n=q).  D[key][q]:
        // lane holds q = l16 (col), keys = ct*16 + quad*4 + rr (rows).
        float4v sacc[4] = {};
        #pragma unroll
        for (int ks = 0; ks < 2; ++ks) {
            const int phb = (ks * 4 + quad) ^ (l16 & 7);
            short8 bq8 = *(short8*)&Qs[qrow * 64 + phb * 8];
            #pragma unroll
            for (int ct = 0; ct < 4; ++ct) {
                const int krow = ct * 16 + l16;
                const int pha = (ks * 4 + quad) ^ (krow & 7);
                short8 ak = *(short8*)&Ks[cur][krow * 64 + pha * 8];
                sacc[ct] = __builtin_amdgcn_mfma_f32_16x16x32_bf16(
                    ak, bq8, sacc[ct], 0, 0, 0);
            }
        }

        // exp2 + (boundary-only) mask + rowsum + packed P write
        const bool full = ((kt + 1) * 64 <= len);
        #pragma unroll
        for (int ct = 0; ct < 4; ++ct) {
            float v0 = __builtin_amdgcn_exp2f(sacc[ct][0]);
            float v1 = __builtin_amdgcn_exp2f(sacc[ct][1]);
            float v2 = __builtin_amdgcn_exp2f(sacc[ct][2]);
            float v3 = __builtin_amdgcn_exp2f(sacc[ct][3]);
            if (!full) {
                const int kb0 = kt * 64 + ct * 16 + quad * 4;
                v0 = (kb0 + 0 < len) ? v0 : 0.f;
                v1 = (kb0 + 1 < len) ? v1 : 0.f;
                v2 = (kb0 + 2 < len) ? v2 : 0.f;
                v3 = (kb0 + 3 < len) ? v3 : 0.f;
            }
            rs += (v0 + v1) + (v2 + v3);
            uint2 w;
            w.x = pk2(v0, v1);
            w.y = pk2(v2, v3);
            const int c8 = (ct * 4 + quad) ^ e8;        // 8B-chunk swizzle
            *(uint2*)&Ps[qrow * 64 + c8 * 4] = w;
        }

        // P @ V: A = P-frag (m=q, k=key), B = V-frag from Vs (n=d).
        // Strip is wave-private: same-wave LDS RAW, no barrier needed.
        #pragma unroll
        for (int ks = 0; ks < 2; ++ks) {
            const int pp = ((ks * 4 + quad) * 2) ^ e8;   // first 8B chunk (even)
            short8 ap = *(short8*)&Ps[qrow * 64 + pp * 4];
            #pragma unroll
            for (int ct = 0; ct < 4; ++ct) {
                const int vrow = ct * 16 + l16;
                const int phv = (ks * 4 + quad) ^ (vrow & 7);
                short8 vv = *(short8*)&Vs[cur][vrow * 64 + phv * 8];
                cacc[ct] = __builtin_amdgcn_mfma_f32_16x16x32_bf16(
                    ap, vv, cacc[ct], 0, 0, 0);
            }
        }
        __syncthreads();   // next-stage glds drained; buf[cur] free for kt+2
    }

    // row-sum: lane holds partial for q = l16-group; reduce across quads
    rs += __shfl_xor(rs, 16);
    rs += __shfl_xor(rs, 32);

    // normalize + store fp32.  C-layout: col = d-offset = l16, row = q-offset
    // = quad*4+rr; fetch rs(q=quad*4+rr) from lane group via width-16 shuffle.
    #pragma unroll
    for (int rr = 0; rr < 4; ++rr) {
        const float rsq = __shfl(rs, quad * 4 + rr, 16);
        const float inv = 1.0f / (rsq + 1e-8f);
        const int q = q0 + wid * 16 + quad * 4 + rr;
        #pragma unroll
        for (int ct = 0; ct < 4; ++ct) {
            const int d = h * 64 + ct * 16 + l16;
            out[((size_t)b * S_ + q) * D_ + d] = cacc[ct][rr] * inv;
        }
    }
}

// ---------------------------------------------------------------------------
extern "C" void kernel_launch(void* const* d_in, const int* in_sizes, int n_in,
                              void* d_out, int out_size, void* d_ws, size_t ws_size,
                              hipStream_t stream)
{
    const float* Q   = (const float*)d_in[0];
    const int*   len = (const int*)d_in[1];
    const float* Wq  = (const float*)d_in[2];
    const float* bq  = (const float*)d_in[3];
    const float* Wk  = (const float*)d_in[4];
    const float* bk  = (const float*)d_in[5];
    const float* Wv  = (const float*)d_in[6];
    const float* bv  = (const float*)d_in[7];
    float* out = (float*)d_out;

    ushort* ws  = (ushort*)d_ws;
    ushort* Xb  = ws;                                   // 4M bf16 = 8 MB
    ushort* Wt  = ws + (size_t)M_ * D_;                 // 3M bf16 = 6 MB
    ushort* qkv = Wt + (size_t)3 * D_ * D_;             // 12M bf16 = 24 MB

    dim3 gPr(16, 16, 11);
    prep<<<gPr, 256, 0, stream>>>(Q, Wq, Wk, Wv, Xb, Wt);

    dim3 gP(M_ / 64, D_ / 128);
    proj_gemm<<<gP, 256, 0, stream>>>(Xb, Wt, bq, bk, bv, len, qkv);

    dim3 gA(S_ / 64, H_, B_);
    attention<<<gA, 256, 0, stream>>>(qkv, len, out);
}

// Round 8
// 156.166 us; speedup vs baseline: 1.1200x; 1.0067x over previous
//
#include <hip/hip_runtime.h>
#include <hip/hip_bf16.h>

#define B_  2
#define S_  2048
#define D_  1024
#define H_  16
#define DK_ 64
#define M_  (B_ * S_)   // 4096

typedef short short8 __attribute__((ext_vector_type(8)));
typedef float float4v __attribute__((ext_vector_type(4)));

// log2(e)/8 : folded into Q at projection so attention exp is a bare v_exp_f32
#define QSCALE 0.18033688011112042f

static __device__ __forceinline__ ushort f32_to_bf16bits(float f) {
    union { __hip_bfloat16 h; ushort u; } cv;
    cv.h = __float2bfloat16(f);
    return cv.u;
}

// async global->LDS, 16B per lane (lands at wave-uniform base + lane*16)
static __device__ __forceinline__ void glds16(const ushort* g, ushort* l) {
    __builtin_amdgcn_global_load_lds(
        (const __attribute__((address_space(1))) unsigned int*)g,
        (__attribute__((address_space(3))) unsigned int*)l, 16, 0, 0);
}

// ---------------------------------------------------------------------------
// prep: z in [0,3) -> transpose+convert W_z[k][n] fp32 -> Wt[n][k] bf16
//       z in [3,11) -> convert X fp32 -> bf16
// ---------------------------------------------------------------------------
__global__ __launch_bounds__(256) void prep(
    const float* __restrict__ X, const float* __restrict__ W0,
    const float* __restrict__ W1, const float* __restrict__ W2,
    ushort* __restrict__ Xb, ushort* __restrict__ Wt)
{
    const int z = blockIdx.z;
    const int t = threadIdx.x;

    if (z >= 3) {   // convert X
        const int blk = (z - 3) * 256 + blockIdx.y * 16 + blockIdx.x;
        const int i = blk * 2048 + t * 8;
        float4v a = *(const float4v*)(X + i);
        float4v b = *(const float4v*)(X + i + 4);
        short8 o;
        o[0] = (short)f32_to_bf16bits(a[0]); o[1] = (short)f32_to_bf16bits(a[1]);
        o[2] = (short)f32_to_bf16bits(a[2]); o[3] = (short)f32_to_bf16bits(a[3]);
        o[4] = (short)f32_to_bf16bits(b[0]); o[5] = (short)f32_to_bf16bits(b[1]);
        o[6] = (short)f32_to_bf16bits(b[2]); o[7] = (short)f32_to_bf16bits(b[3]);
        *(short8*)(Xb + i) = o;
        return;
    }

    const float* W = (z == 0) ? W0 : ((z == 1) ? W1 : W2);
    ushort* out = Wt + (size_t)z * D_ * D_;

    __shared__ ushort tile[64 * 72];
    int n0 = blockIdx.x * 64, k0 = blockIdx.y * 64;
    int r = t >> 3, g = t & 7;

    #pragma unroll
    for (int p = 0; p < 2; ++p) {
        int rr = r + p * 32;
        const float* src = W + (size_t)(k0 + rr) * D_ + n0 + g * 8;
        float4v a = *(const float4v*)src;
        float4v b = *(const float4v*)(src + 4);
        short8 o;
        o[0] = (short)f32_to_bf16bits(a[0]); o[1] = (short)f32_to_bf16bits(a[1]);
        o[2] = (short)f32_to_bf16bits(a[2]); o[3] = (short)f32_to_bf16bits(a[3]);
        o[4] = (short)f32_to_bf16bits(b[0]); o[5] = (short)f32_to_bf16bits(b[1]);
        o[6] = (short)f32_to_bf16bits(b[2]); o[7] = (short)f32_to_bf16bits(b[3]);
        *(short8*)&tile[rr * 72 + g * 8] = o;
    }
    __syncthreads();
    #pragma unroll
    for (int p = 0; p < 2; ++p) {
        int rr = r + p * 32;
        short8 v;
        #pragma unroll
        for (int i = 0; i < 8; ++i)
            v[i] = (short)tile[(g * 8 + i) * 72 + rr];
        *(short8*)(out + (size_t)(n0 + rr) * D_ + k0 + g * 8) = v;
    }
}

// ---------------------------------------------------------------------------
// FUSED-z QKV projection: one block = (m-tile 64, n-tile 128) computing q, k
// AND v.  A staged once, 48 MFMA per barrier.  56 KB LDS = 2 blocks/CU.
// k/v work skipped (block-uniform) when this m-tile is beyond length[b].
// z==0 (Q) epilogue folds score-scale*log2(e) into the values.
// ---------------------------------------------------------------------------
__global__ __launch_bounds__(256, 2) void proj_gemm(
    const ushort* __restrict__ X,    // [4096][1024] bf16
    const ushort* __restrict__ Wt,   // [3][1024][1024] bf16, n-major
    const float* __restrict__ b0, const float* __restrict__ b1,
    const float* __restrict__ b2,
    const int* __restrict__ length,
    ushort* __restrict__ qkv)        // [3][4M] bf16
{
    const int m0 = blockIdx.x * 64, n0 = blockIdx.y * 128;
    const int bidx = m0 >> 11;
    const int s0 = m0 & (S_ - 1);
    const bool kv = (s0 < length[bidx]);   // block-uniform

    __shared__ __align__(16) ushort As[64 * 64];        //  8 KB
    __shared__ __align__(16) ushort Bs[3][128 * 64];    // 48 KB

    const int t = threadIdx.x;
    const int lane = t & 63, wid = t >> 6;
    const int quad = lane >> 4, l16 = lane & 15;
    const int wr = wid >> 1, wc = wid & 1;

    float4v accq[2][4] = {}, acck[2][4] = {}, accv[2][4] = {};

    for (int kt = 0; kt < 16; ++kt) {
        const int k0 = kt * 64;
        __syncthreads();
        #pragma unroll
        for (int j = 0; j < 2; ++j) {          // A: 512 chunks, 128/wave
            const int cid = wid * 128 + j * 64 + lane;
            const int row = cid >> 3;
            const int cl  = (cid & 7) ^ (row & 7);
            glds16(X + (size_t)(m0 + row) * D_ + k0 + cl * 8, &As[cid * 8]);
        }
        #pragma unroll
        for (int j = 0; j < 4; ++j) {          // B panels: 1024 chunks each
            const int cid = wid * 256 + j * 64 + lane;
            const int row = cid >> 3;
            const int cl  = (cid & 7) ^ (row & 7);
            const size_t off = (size_t)(n0 + row) * D_ + k0 + cl * 8;
            glds16(Wt + off, &Bs[0][cid * 8]);
            if (kv) {
                glds16(Wt + (size_t)D_ * D_ + off,     &Bs[1][cid * 8]);
                glds16(Wt + (size_t)2 * D_ * D_ + off, &Bs[2][cid * 8]);
            }
        }
        __syncthreads();

        #pragma unroll
        for (int ks = 0; ks < 2; ++ks) {
            short8 a[2];
            #pragma unroll
            for (int i = 0; i < 2; ++i) {
                const int r = wr * 32 + i * 16 + l16;
                const int ph = (ks * 4 + quad) ^ (r & 7);
                a[i] = *(short8*)&As[r * 64 + ph * 8];
            }
            short8 bq[4];
            #pragma unroll
            for (int j = 0; j < 4; ++j) {
                const int r = wc * 64 + j * 16 + l16;
                const int ph = (ks * 4 + quad) ^ (r & 7);
                bq[j] = *(short8*)&Bs[0][r * 64 + ph * 8];
            }
            #pragma unroll
            for (int i = 0; i < 2; ++i)
                #pragma unroll
                for (int j = 0; j < 4; ++j)
                    accq[i][j] = __builtin_amdgcn_mfma_f32_16x16x32_bf16(
                        a[i], bq[j], accq[i][j], 0, 0, 0);
            if (kv) {
                short8 bk[4], bv[4];
                #pragma unroll
                for (int j = 0; j < 4; ++j) {
                    const int r = wc * 64 + j * 16 + l16;
                    const int ph = (ks * 4 + quad) ^ (r & 7);
                    bk[j] = *(short8*)&Bs[1][r * 64 + ph * 8];
                    bv[j] = *(short8*)&Bs[2][r * 64 + ph * 8];
                }
                #pragma unroll
                for (int i = 0; i < 2; ++i)
                    #pragma unroll
                    for (int j = 0; j < 4; ++j) {
                        acck[i][j] = __builtin_amdgcn_mfma_f32_16x16x32_bf16(
                            a[i], bk[j], acck[i][j], 0, 0, 0);
                        accv[i][j] = __builtin_amdgcn_mfma_f32_16x16x32_bf16(
                            a[i], bv[j], accv[i][j], 0, 0, 0);
                    }
            }
        }
    }

    // epilogue: +bias, scatter into head layouts.
    #pragma unroll
    for (int j = 0; j < 4; ++j) {
        const int col = n0 + wc * 64 + j * 16 + l16;
        const int h = col >> 6, dk = col & (DK_ - 1);
        const float bvq = b0[col], bvk = b1[col], bvv = b2[col];
        #pragma unroll
        for (int i = 0; i < 2; ++i) {
            #pragma unroll
            for (int rr = 0; rr < 4; ++rr) {
                const int row = m0 + wr * 32 + i * 16 + quad * 4 + rr;
                const int s = row & (S_ - 1);
                const size_t hdr = ((size_t)(bidx * H_ + h) * S_ + s) * DK_ + dk;
                qkv[hdr] = f32_to_bf16bits((accq[i][j][rr] + bvq) * QSCALE);
                if (kv) {
                    qkv[(size_t)M_ * D_ + hdr] =
                        f32_to_bf16bits(acck[i][j][rr] + bvk);
                    qkv[(size_t)2 * M_ * D_ +
                        ((size_t)(bidx * H_ + h) * DK_ + dk) * S_ + s] =
                        f32_to_bf16bits(accv[i][j][rr] + bvv);
                }
            }
        }
    }
}

// ---------------------------------------------------------------------------
// attention: block = (b, h, 64 q-rows), 4 waves x 16-q strips.
// S^T trick (S^T = K*Q^T) -> packed P writes.  Q frags hoisted (invariant).
// Row-sums via ones-MFMA: racc += P_frag @ ones reuses the PV A-fragment and
// the C-layout lands rowsum(q=quad*4+rr) in the exact lane that normalizes it
// (zero shuffles).  P packed by TRUNCATION (2 VALU/pair; bias cancels in the
// P/sum(P) ratio).  Q pre-scaled at projection: exp = bare v_exp_f32.
// ---------------------------------------------------------------------------
__global__ __launch_bounds__(256, 3) void attention(
    const ushort* __restrict__ qkv, const int* __restrict__ length,
    float* __restrict__ out)
{
    const int b = blockIdx.z, h = blockIdx.y, q0 = blockIdx.x * 64;
    int len = length[b];
    if (len > S_) len = S_;
    if (len < 1) len = 1;
    const int nkt = (len + 63) >> 6;

    const ushort* qb = qkv + ((size_t)(b * H_ + h) * S_ + q0) * DK_;
    const ushort* kb = qkv + (size_t)M_ * D_ + (size_t)(b * H_ + h) * S_ * DK_;
    const ushort* vb = qkv + (size_t)2 * M_ * D_ + (size_t)(b * H_ + h) * DK_ * S_;

    __shared__ __align__(16) ushort Qs[64 * 64];       //  8 KB [q][dk]
    __shared__ __align__(16) ushort Ks[2][64 * 64];    // 16 KB [key][dk]
    __shared__ __align__(16) ushort Vs[2][64 * 64];    // 16 KB [dk][key]
    __shared__ __align__(16) ushort Ps[64 * 64];       //  8 KB [q][key], 8B-swizzle

    const int t = threadIdx.x, lane = t & 63, wid = t >> 6;
    const int quad = lane >> 4, l16 = lane & 15;
    const int qrow = wid * 16 + l16;
    const int e8 = (l16 & 7) << 1;   // even XOR phase for Ps (row&7 == l16&7)

    // stage Q (once) + K/V tile 0
    #pragma unroll
    for (int j = 0; j < 2; ++j) {
        const int cid = wid * 128 + j * 64 + lane;
        const int row = cid >> 3;
        const int cl  = (cid & 7) ^ (row & 7);
        glds16(qb + (size_t)row * DK_ + cl * 8, &Qs[cid * 8]);
        glds16(kb + (size_t)row * DK_ + cl * 8, &Ks[0][cid * 8]);
        glds16(vb + (size_t)row * S_ + cl * 8,  &Vs[0][cid * 8]);
    }
    __syncthreads();

    // hoist Q fragments (loop-invariant)
    short8 qfrag[2];
    #pragma unroll
    for (int ks = 0; ks < 2; ++ks) {
        const int phb = (ks * 4 + quad) ^ (l16 & 7);
        qfrag[ks] = *(short8*)&Qs[qrow * 64 + phb * 8];
    }

    // bf16 ones fragment for the rowsum MFMA
    short8 ones8;
    #pragma unroll
    for (int i = 0; i < 8; ++i) ones8[i] = (short)0x3F80;

    float4v cacc[4] = {};
    float4v racc = {};

    for (int kt = 0; kt < nkt; ++kt) {
        const int cur = kt & 1, nxt = cur ^ 1;
        if (kt + 1 < nkt) {
            #pragma unroll
            for (int j = 0; j < 2; ++j) {
                const int cid = wid * 128 + j * 64 + lane;
                const int row = cid >> 3;
                const int cl  = (cid & 7) ^ (row & 7);
                glds16(kb + (size_t)((kt + 1) * 64 + row) * DK_ + cl * 8,
                       &Ks[nxt][cid * 8]);
                glds16(vb + (size_t)row * S_ + (kt + 1) * 64 + cl * 8,
                       &Vs[nxt][cid * 8]);
            }
        }

        // S^T tile: A = K-frag (m=key), B = Q-frag (n=q).  D[key][q]:
        // lane holds q = l16 (col), keys = ct*16 + quad*4 + rr (rows).
        float4v sacc[4] = {};
        #pragma unroll
        for (int ks = 0; ks < 2; ++ks) {
            #pragma unroll
            for (int ct = 0; ct < 4; ++ct) {
                const int krow = ct * 16 + l16;
                const int pha = (ks * 4 + quad) ^ (krow & 7);
                short8 ak = *(short8*)&Ks[cur][krow * 64 + pha * 8];
                sacc[ct] = __builtin_amdgcn_mfma_f32_16x16x32_bf16(
                    ak, qfrag[ks], sacc[ct], 0, 0, 0);
            }
        }

        // exp2 + (boundary-only) mask + truncation-packed P write
        const bool full = ((kt + 1) * 64 <= len);
        #pragma unroll
        for (int ct = 0; ct < 4; ++ct) {
            float v0 = __builtin_amdgcn_exp2f(sacc[ct][0]);
            float v1 = __builtin_amdgcn_exp2f(sacc[ct][1]);
            float v2 = __builtin_amdgcn_exp2f(sacc[ct][2]);
            float v3 = __builtin_amdgcn_exp2f(sacc[ct][3]);
            if (!full) {
                const int kb0 = kt * 64 + ct * 16 + quad * 4;
                v0 = (kb0 + 0 < len) ? v0 : 0.f;
                v1 = (kb0 + 1 < len) ? v1 : 0.f;
                v2 = (kb0 + 2 < len) ? v2 : 0.f;
                v3 = (kb0 + 3 < len) ? v3 : 0.f;
            }
            uint2 w;
            w.x = (__float_as_uint(v0) >> 16) | (__float_as_uint(v1) & 0xFFFF0000u);
            w.y = (__float_as_uint(v2) >> 16) | (__float_as_uint(v3) & 0xFFFF0000u);
            const int c8 = (ct * 4 + quad) ^ e8;        // 8B-chunk swizzle
            *(uint2*)&Ps[qrow * 64 + c8 * 4] = w;
        }

        // P @ V  (+ rowsum via ones-MFMA, reusing the A-fragment).
        // Strip is wave-private: same-wave LDS RAW, no barrier needed.
        #pragma unroll
        for (int ks = 0; ks < 2; ++ks) {
            const int pp = ((ks * 4 + quad) * 2) ^ e8;   // first 8B chunk (even)
            short8 ap = *(short8*)&Ps[qrow * 64 + pp * 4];
            #pragma unroll
            for (int ct = 0; ct < 4; ++ct) {
                const int vrow = ct * 16 + l16;
                const int phv = (ks * 4 + quad) ^ (vrow & 7);
                short8 vv = *(short8*)&Vs[cur][vrow * 64 + phv * 8];
                cacc[ct] = __builtin_amdgcn_mfma_f32_16x16x32_bf16(
                    ap, vv, cacc[ct], 0, 0, 0);
            }
            racc = __builtin_amdgcn_mfma_f32_16x16x32_bf16(
                ap, ones8, racc, 0, 0, 0);
        }
        __syncthreads();   // next-stage glds drained; buf[cur] free for kt+2
    }

    // normalize + store fp32.  racc[rr] holds rowsum for q = quad*4+rr in
    // every l16 lane -- exactly where cacc[ct][rr] needs it.  No shuffles.
    #pragma unroll
    for (int rr = 0; rr < 4; ++rr) {
        const float inv = 1.0f / (racc[rr] + 1e-8f);
        const int q = q0 + wid * 16 + quad * 4 + rr;
        #pragma unroll
        for (int ct = 0; ct < 4; ++ct) {
            const int d = h * 64 + ct * 16 + l16;
            out[((size_t)b * S_ + q) * D_ + d] = cacc[ct][rr] * inv;
        }
    }
}

// ---------------------------------------------------------------------------
extern "C" void kernel_launch(void* const* d_in, const int* in_sizes, int n_in,
                              void* d_out, int out_size, void* d_ws, size_t ws_size,
                              hipStream_t stream)
{
    const float* Q   = (const float*)d_in[0];
    const int*   len = (const int*)d_in[1];
    const float* Wq  = (const float*)d_in[2];
    const float* bq  = (const float*)d_in[3];
    const float* Wk  = (const float*)d_in[4];
    const float* bk  = (const float*)d_in[5];
    const float* Wv  = (const float*)d_in[6];
    const float* bv  = (const float*)d_in[7];
    float* out = (float*)d_out;

    ushort* ws  = (ushort*)d_ws;
    ushort* Xb  = ws;                                   // 4M bf16 = 8 MB
    ushort* Wt  = ws + (size_t)M_ * D_;                 // 3M bf16 = 6 MB
    ushort* qkv = Wt + (size_t)3 * D_ * D_;             // 12M bf16 = 24 MB

    dim3 gPr(16, 16, 11);
    prep<<<gPr, 256, 0, stream>>>(Q, Wq, Wk, Wv, Xb, Wt);

    dim3 gP(M_ / 64, D_ / 128);
    proj_gemm<<<gP, 256, 0, stream>>>(Xb, Wt, bq, bk, bv, len, qkv);

    dim3 gA(S_ / 64, H_, B_);
    attention<<<gA, 256, 0, stream>>>(qkv, len, out);
}